// Round 1
// baseline (1619.743 us; speedup 1.0000x reference)
//
#include <hip/hip_runtime.h>

typedef _Float16 f16;
typedef __attribute__((ext_vector_type(8))) _Float16 f16x8;
typedef __attribute__((ext_vector_type(4))) float f32x4;

constexpr int NN = 10000;
constexpr int EE = 320000;
constexpr int KPAD = 10016;   // 313 * 32
constexpr int KSTEPS = 313;

// ---------------------------------------------------------------------------
// Build X^T in f16: XT[n][k], n in [0,160) (158 real cols), k in [0,10016)
// (zero padded). Tiled transpose through LDS so both global sides coalesce.
// ---------------------------------------------------------------------------
__global__ __launch_bounds__(256) void k_prep_xt(const float* __restrict__ x,
                                                 const float* __restrict__ wf,
                                                 f16* __restrict__ XT) {
  __shared__ __align__(16) f16 tile[64][33];
  const int k0 = blockIdx.x * 64, n0 = blockIdx.y * 32;
  const int t = threadIdx.x;
#pragma unroll
  for (int i = 0; i < 8; ++i) {
    int idx = t + i * 256;
    int kl = idx >> 5, nl = idx & 31;
    int k = k0 + kl, n = n0 + nl;
    float v = 0.f;
    if (k < NN && n < 158) v = (n < 128) ? x[k * 128 + n] : wf[k * 30 + (n - 128)];
    tile[kl][nl] = (f16)v;
  }
  __syncthreads();
#pragma unroll
  for (int i = 0; i < 8; ++i) {
    int idx = t + i * 256;
    int nl = idx >> 6, kl = idx & 63;
    int k = k0 + kl;
    if (k < KPAD) XT[(n0 + nl) * KPAD + k] = tile[kl][nl];
  }
}

// ---------------------------------------------------------------------------
// Split-K GEMM: part[hop][chunk][m][n] = hop_mat[m, krange] @ X[krange, n]
// 64-row tile, all 160 cols, f16 MFMA, fp32 accumulate. HBM-bound on A reads.
// grid = (157, NC, 3), block = 256 (4 waves, 16 rows each).
// ---------------------------------------------------------------------------
__global__ __launch_bounds__(256) void k_hop_gemm(const float* __restrict__ A1,
    const float* __restrict__ A2, const float* __restrict__ A3,
    const f16* __restrict__ XT, float* __restrict__ part, int steps_per) {
  const float* A = blockIdx.z == 0 ? A1 : (blockIdx.z == 1 ? A2 : A3);
  __shared__ __align__(16) f16 sA[64 * 40];
  __shared__ __align__(16) f16 sB[160 * 40];
  const int tid = threadIdx.x;
  const int wave = tid >> 6, lane = tid & 63;
  const int m0 = blockIdx.x * 64;
  const int s0 = blockIdx.y * steps_per;
  const int s1 = min(KSTEPS, s0 + steps_per);
  const f32x4 zero = {0.f, 0.f, 0.f, 0.f};
  f32x4 acc[10];
#pragma unroll
  for (int i = 0; i < 10; ++i) acc[i] = zero;

  const int r = tid >> 2;
  const int kk = (tid & 3) * 8;
  int gr = m0 + r; if (gr >= NN) gr = NN - 1;   // clamp; OOB rows never stored
  const float* Arow = A + (size_t)gr * NN;
  const int afo = (wave * 16 + (lane & 15)) * 40 + (lane >> 4) * 8;
  const int bfo = (lane & 15) * 40 + (lane >> 4) * 8;

  for (int s = s0; s < s1; ++s) {
    const int k0 = s * 32;
    f16* ad = &sA[r * 40 + kk];
    if (k0 + 32 <= NN) {
      f32x4 v0 = *(const f32x4*)(Arow + k0 + kk);
      f32x4 v1 = *(const f32x4*)(Arow + k0 + kk + 4);
      ad[0] = (f16)v0.x; ad[1] = (f16)v0.y; ad[2] = (f16)v0.z; ad[3] = (f16)v0.w;
      ad[4] = (f16)v1.x; ad[5] = (f16)v1.y; ad[6] = (f16)v1.z; ad[7] = (f16)v1.w;
    } else {               // K tail (k >= 10000 must be exact zero)
#pragma unroll
      for (int j = 0; j < 8; ++j) {
        int kg = k0 + kk + j;
        ad[j] = (f16)(kg < NN ? Arow[kg] : 0.f);
      }
    }
    // B tile: straight f16 copy of XT[n][k0..k0+32), 160 rows
#pragma unroll
    for (int i = 0; i < 3; ++i) {
      int u = tid + i * 256;
      if (u < 640) {
        int n = u >> 2, c = (u & 3) * 8;
        *(f16x8*)&sB[n * 40 + c] = *(const f16x8*)&XT[n * KPAD + k0 + c];
      }
    }
    __syncthreads();
    f16x8 af = *(const f16x8*)&sA[afo];
#pragma unroll
    for (int t = 0; t < 10; ++t) {
      f16x8 bf = *(const f16x8*)&sB[t * 16 * 40 + bfo];
      acc[t] = __builtin_amdgcn_mfma_f32_16x16x32_f16(af, bf, acc[t], 0, 0, 0);
    }
    __syncthreads();
  }
  float* dst = part + (size_t)(blockIdx.z * gridDim.y + blockIdx.y) * NN * 160;
  const int cr = (lane >> 4) * 4, cc = lane & 15;
  const int mbase = m0 + wave * 16 + cr;
#pragma unroll
  for (int t = 0; t < 10; ++t) {
#pragma unroll
    for (int i = 0; i < 4; ++i) {
      int m = mbase + i;
      if (m < NN) dst[(size_t)m * 160 + t * 16 + cc] = acc[t][i];
    }
  }
}

// ---------------------------------------------------------------------------
// MLP layer 1: H[y][m][j] = Y_y[m,:158] @ W1[y] + b1[y]
// Y_0 = X built on the fly; Y_{1..3} = sum of NC split-K partials.
// grid = (157, 4), block = 256. 64-row tile, 256 out cols, K = 160 (5 steps).
// ---------------------------------------------------------------------------
__global__ __launch_bounds__(256) void k_mlp1(const float* __restrict__ x,
    const float* __restrict__ wf, const float* __restrict__ part,
    const float* __restrict__ W1, const float* __restrict__ b1,
    float* __restrict__ H, int NC) {
  const int y = blockIdx.y;
  __shared__ __align__(16) f16 sA[64 * 40];
  __shared__ __align__(16) f16 sB[256 * 40];
  const int tid = threadIdx.x, wave = tid >> 6, lane = tid & 63;
  const int m0 = blockIdx.x * 64;
  const f32x4 zero = {0.f, 0.f, 0.f, 0.f};
  f32x4 acc[16];
#pragma unroll
  for (int i = 0; i < 16; ++i) acc[i] = zero;
  const int r = tid >> 2, kk = (tid & 3) * 8;
  int gr = m0 + r; if (gr >= NN) gr = NN - 1;
  const float* W = W1 + (size_t)y * 158 * 256;
  const int afo = (wave * 16 + (lane & 15)) * 40 + (lane >> 4) * 8;
  const int bfo = (lane & 15) * 40 + (lane >> 4) * 8;

  for (int s = 0; s < 5; ++s) {
    const int k0 = s * 32;
    float av[8];
    if (y == 0) {
#pragma unroll
      for (int j = 0; j < 8; ++j) {
        int c = k0 + kk + j;
        av[j] = (c < 128) ? x[gr * 128 + c]
                          : (c < 158 ? wf[gr * 30 + (c - 128)] : 0.f);
      }
    } else {
#pragma unroll
      for (int j = 0; j < 8; ++j) av[j] = 0.f;
      const float* p = part + ((size_t)(y - 1) * NC * NN + gr) * 160 + k0 + kk;
      for (int c = 0; c < NC; ++c) {
        f32x4 v0 = *(const f32x4*)(p);
        f32x4 v1 = *(const f32x4*)(p + 4);
        av[0] += v0.x; av[1] += v0.y; av[2] += v0.z; av[3] += v0.w;
        av[4] += v1.x; av[5] += v1.y; av[6] += v1.z; av[7] += v1.w;
        p += (size_t)NN * 160;
      }
    }
    f16* ad = &sA[r * 40 + kk];
#pragma unroll
    for (int j = 0; j < 8; ++j) ad[j] = (f16)av[j];
    // W1 slab rows [k0, k0+32) staged transposed (rows >= 158 zero)
#pragma unroll
    for (int i = 0; i < 32; ++i) {
      int idx = tid + i * 256;
      int kl = idx >> 8, n = idx & 255;
      int kg = k0 + kl;
      float v = (kg < 158) ? W[kg * 256 + n] : 0.f;
      sB[n * 40 + kl] = (f16)v;
    }
    __syncthreads();
    f16x8 af = *(const f16x8*)&sA[afo];
#pragma unroll
    for (int t = 0; t < 16; ++t) {
      f16x8 bf = *(const f16x8*)&sB[t * 16 * 40 + bfo];
      acc[t] = __builtin_amdgcn_mfma_f32_16x16x32_f16(af, bf, acc[t], 0, 0, 0);
    }
    __syncthreads();
  }
  const float* bias = b1 + y * 256;
  float* Hy = H + (size_t)y * NN * 256;
  const int cr = (lane >> 4) * 4, cc = lane & 15;
  const int mbase = m0 + wave * 16 + cr;
#pragma unroll
  for (int t = 0; t < 16; ++t) {
    int col = t * 16 + cc;
    float bv = bias[col];
#pragma unroll
    for (int i = 0; i < 4; ++i) {
      int m = mbase + i;
      if (m < NN) Hy[(size_t)m * 256 + col] = acc[t][i] + bv;
    }
  }
}

// Column sums / sums of squares of H (batch-norm batch stats).
__global__ __launch_bounds__(256) void k_stats(const float* __restrict__ H,
    float* __restrict__ ssum, float* __restrict__ ssq) {
  const int y = blockIdx.y, t = threadIdx.x;
  const int m0 = blockIdx.x * 64;
  const int rows = min(64, NN - m0);
  const float* Hy = H + ((size_t)y * NN + m0) * 256 + t;
  float s1 = 0.f, s2 = 0.f;
  for (int r = 0; r < rows; ++r) {
    float v = Hy[(size_t)r * 256];
    s1 += v; s2 += v * v;
  }
  atomicAdd(&ssum[y * 256 + t], s1);
  atomicAdd(&ssq[y * 256 + t], s2);
}

__global__ __launch_bounds__(256) void k_bnstats(const float* __restrict__ ssum,
    const float* __restrict__ ssq, const float* __restrict__ g,
    const float* __restrict__ be, float* __restrict__ ab) {
  int i = blockIdx.x * 256 + threadIdx.x;
  if (i >= 1024) return;
  float mu = ssum[i] * (1.f / NN);
  float var = ssq[i] * (1.f / NN) - mu * mu;
  float rs = rsqrtf(var + 1e-5f);
  float a = g[i] * rs;
  ab[i * 2] = a;
  ab[i * 2 + 1] = be[i] - mu * a;
}

// ---------------------------------------------------------------------------
// MLP layer 2 + sum over 4 sub-layers:
// out[m][256+j] = sum_y relu(a_y * H_y[m] + sh_y) @ W2[y] + sum_y b2[y]
// grid = 313, block = 256. 32-row tile, K = 4*256 accumulated in one acc.
// ---------------------------------------------------------------------------
__global__ __launch_bounds__(256) void k_mlp2(const float* __restrict__ H,
    const float* __restrict__ ab, const float* __restrict__ W2,
    const float* __restrict__ b2, float* __restrict__ out) {
  __shared__ __align__(16) f16 sA[32 * 40];
  __shared__ __align__(16) f16 sB[256 * 40];
  __shared__ float sAB[512];
  const int tid = threadIdx.x, wave = tid >> 6, lane = tid & 63;
  const int m0 = blockIdx.x * 32;
  const int rt = wave >> 1, ct0 = (wave & 1) * 8;
  const f32x4 zero = {0.f, 0.f, 0.f, 0.f};
  f32x4 acc[8];
#pragma unroll
  for (int i = 0; i < 8; ++i) acc[i] = zero;
  const int r = tid >> 3, kk = (tid & 7) * 4;
  int gr = m0 + r; if (gr >= NN) gr = NN - 1;
  const int afo = (rt * 16 + (lane & 15)) * 40 + (lane >> 4) * 8;
  const int bfo = (lane & 15) * 40 + (lane >> 4) * 8;

  for (int y = 0; y < 4; ++y) {
    __syncthreads();
    sAB[tid] = ab[y * 512 + tid];
    sAB[256 + tid] = ab[y * 512 + 256 + tid];
    __syncthreads();
    const float* Hy = H + (size_t)y * NN * 256;
    const float* Wy = W2 + (size_t)y * 256 * 256;
    for (int ks = 0; ks < 8; ++ks) {
      const int k0 = ks * 32;
      f32x4 hv = *(const f32x4*)(Hy + (size_t)gr * 256 + k0 + kk);
      float hvv[4] = {hv.x, hv.y, hv.z, hv.w};
      f16* ad = &sA[r * 40 + kk];
#pragma unroll
      for (int j = 0; j < 4; ++j) {
        int c = k0 + kk + j;
        float v = fmaxf(sAB[c * 2] * hvv[j] + sAB[c * 2 + 1], 0.f);
        ad[j] = (f16)v;
      }
#pragma unroll
      for (int i = 0; i < 32; ++i) {
        int idx = tid + i * 256;
        int kl = idx >> 8, n = idx & 255;
        sB[n * 40 + kl] = (f16)Wy[(k0 + kl) * 256 + n];
      }
      __syncthreads();
      f16x8 af = *(const f16x8*)&sA[afo];
#pragma unroll
      for (int t = 0; t < 8; ++t) {
        f16x8 bf = *(const f16x8*)&sB[(ct0 + t) * 16 * 40 + bfo];
        acc[t] = __builtin_amdgcn_mfma_f32_16x16x32_f16(af, bf, acc[t], 0, 0, 0);
      }
      __syncthreads();
    }
  }
  const int cr = (lane >> 4) * 4, cc = lane & 15;
  const int mbase = m0 + rt * 16 + cr;
#pragma unroll
  for (int t = 0; t < 8; ++t) {
    int col = (ct0 + t) * 16 + cc;
    float bsum = b2[col] + b2[256 + col] + b2[512 + col] + b2[768 + col];
#pragma unroll
    for (int i = 0; i < 4; ++i) {
      int m = mbase + i;
      if (m < NN) out[(size_t)m * 512 + 256 + col] = acc[t][i] + bsum;
    }
  }
}

// ---------------------------------------------------------------------------
// GCN: generic C[10000 x 256] = A[10000 x K] @ B[K x 256], f16 MFMA.
// ---------------------------------------------------------------------------
__global__ __launch_bounds__(256) void k_gemm256(const float* __restrict__ A, int K,
    const float* __restrict__ B, float* __restrict__ C) {
  __shared__ __align__(16) f16 sA[64 * 40];
  __shared__ __align__(16) f16 sB[256 * 40];
  const int tid = threadIdx.x, wave = tid >> 6, lane = tid & 63;
  const int m0 = blockIdx.x * 64;
  const f32x4 zero = {0.f, 0.f, 0.f, 0.f};
  f32x4 acc[16];
#pragma unroll
  for (int i = 0; i < 16; ++i) acc[i] = zero;
  const int r = tid >> 2, kk = (tid & 3) * 8;
  int gr = m0 + r; if (gr >= NN) gr = NN - 1;
  const int afo = (wave * 16 + (lane & 15)) * 40 + (lane >> 4) * 8;
  const int bfo = (lane & 15) * 40 + (lane >> 4) * 8;
  for (int k0 = 0; k0 < K; k0 += 32) {
    f32x4 v0 = *(const f32x4*)(A + (size_t)gr * K + k0 + kk);
    f32x4 v1 = *(const f32x4*)(A + (size_t)gr * K + k0 + kk + 4);
    f16* ad = &sA[r * 40 + kk];
    ad[0] = (f16)v0.x; ad[1] = (f16)v0.y; ad[2] = (f16)v0.z; ad[3] = (f16)v0.w;
    ad[4] = (f16)v1.x; ad[5] = (f16)v1.y; ad[6] = (f16)v1.z; ad[7] = (f16)v1.w;
#pragma unroll
    for (int i = 0; i < 32; ++i) {
      int idx = tid + i * 256;
      int kl = idx >> 8, n = idx & 255;
      sB[n * 40 + kl] = (f16)B[(k0 + kl) * 256 + n];
    }
    __syncthreads();
    f16x8 af = *(const f16x8*)&sA[afo];
#pragma unroll
    for (int t = 0; t < 16; ++t) {
      f16x8 bf = *(const f16x8*)&sB[t * 16 * 40 + bfo];
      acc[t] = __builtin_amdgcn_mfma_f32_16x16x32_f16(af, bf, acc[t], 0, 0, 0);
    }
    __syncthreads();
  }
  const int cr = (lane >> 4) * 4, cc = lane & 15;
  const int mbase = m0 + wave * 16 + cr;
#pragma unroll
  for (int t = 0; t < 16; ++t) {
    int col = t * 16 + cc;
#pragma unroll
    for (int i = 0; i < 4; ++i) {
      int m = mbase + i;
      if (m < NN) C[(size_t)m * 256 + col] = acc[t][i];
    }
  }
}

__global__ __launch_bounds__(256) void k_count(const int* __restrict__ edges,
                                               unsigned* __restrict__ cnt) {
  int e = blockIdx.x * 256 + threadIdx.x;
  if (e < EE) atomicAdd(&cnt[edges[EE + e]], 1u);
}

__global__ __launch_bounds__(256) void k_dinv(const unsigned* __restrict__ cnt,
                                              float* __restrict__ dinv) {
  int i = blockIdx.x * 256 + threadIdx.x;
  if (i < NN) dinv[i] = rsqrtf((float)cnt[i] + 1.0f);  // + self loop
}

// Single-block exclusive scan of (indeg + 1) -> rowptr / cursor.
__global__ __launch_bounds__(256) void k_scan(const unsigned* __restrict__ cnt,
    int* __restrict__ rowptr, int* __restrict__ cursor) {
  __shared__ int ps[257];
  const int t = threadIdx.x;
  const int base = t * 40;
  int local[40];
  int s = 0;
#pragma unroll
  for (int i = 0; i < 40; ++i) {
    int rr = base + i;
    int v = (rr < NN) ? ((int)cnt[rr] + 1) : 0;
    local[i] = s; s += v;
  }
  ps[t + 1] = s;
  if (t == 0) ps[0] = 0;
  __syncthreads();
  if (t == 0) {
    int a = 0;
    for (int i = 1; i <= 256; ++i) { a += ps[i]; ps[i] = a; }
  }
  __syncthreads();
  int off = ps[t];
#pragma unroll
  for (int i = 0; i < 40; ++i) {
    int rr = base + i;
    if (rr < NN) { rowptr[rr] = off + local[i]; cursor[rr] = off + local[i]; }
  }
  if (t == 255) rowptr[NN] = ps[256];
}

__global__ __launch_bounds__(256) void k_fill(const int* __restrict__ edges,
    const float* __restrict__ dinv, int* __restrict__ cursor,
    int* __restrict__ ecol, float* __restrict__ eval) {
  int i = blockIdx.x * 256 + threadIdx.x;
  if (i < EE) {
    int s = edges[i], d = edges[EE + i];
    int p = atomicAdd(&cursor[d], 1);
    ecol[p] = s;
    eval[p] = dinv[s] * dinv[d];
  } else if (i < EE + NN) {
    int rr = i - EE;
    int p = atomicAdd(&cursor[rr], 1);
    ecol[p] = rr;
    float dv = dinv[rr];
    eval[p] = dv * dv;
  }
}

// out[row][c] = relu(bias[c] + sum_e val[e] * hw[col[e]][c]); one block per row.
__global__ __launch_bounds__(256) void k_prop(const float* __restrict__ hw,
    const int* __restrict__ rowptr, const int* __restrict__ ecol,
    const float* __restrict__ eval, const float* __restrict__ bias,
    float* __restrict__ out, int ostride) {
  const int rr = blockIdx.x, c = threadIdx.x;
  const int e1 = rowptr[rr + 1];
  float acc = 0.f;
  int e = rowptr[rr];
  for (; e + 4 <= e1; e += 4) {
    int c0 = ecol[e], c1 = ecol[e + 1], c2 = ecol[e + 2], c3 = ecol[e + 3];
    float v0 = eval[e], v1 = eval[e + 1], v2 = eval[e + 2], v3 = eval[e + 3];
    acc += v0 * hw[(size_t)c0 * 256 + c];
    acc += v1 * hw[(size_t)c1 * 256 + c];
    acc += v2 * hw[(size_t)c2 * 256 + c];
    acc += v3 * hw[(size_t)c3 * 256 + c];
  }
  for (; e < e1; ++e) acc += eval[e] * hw[(size_t)ecol[e] * 256 + c];
  out[(size_t)rr * ostride + c] = fmaxf(acc + bias[c], 0.f);
}

// ---------------------------------------------------------------------------
extern "C" void kernel_launch(void* const* d_in, const int* in_sizes, int n_in,
                              void* d_out, int out_size, void* d_ws, size_t ws_size,
                              hipStream_t stream) {
  const float* x     = (const float*)d_in[0];
  const int*   edges = (const int*)d_in[1];
  const float* wf    = (const float*)d_in[2];
  const float* hop1  = (const float*)d_in[3];
  const float* hop2  = (const float*)d_in[4];
  const float* hop3  = (const float*)d_in[5];
  const float* gW1   = (const float*)d_in[6];
  const float* gb1   = (const float*)d_in[7];
  const float* gW2   = (const float*)d_in[8];
  const float* gb2   = (const float*)d_in[9];
  const float* gW3   = (const float*)d_in[10];
  const float* gb3   = (const float*)d_in[11];
  const float* sW1   = (const float*)d_in[12];
  const float* sb1   = (const float*)d_in[13];
  const float* sg    = (const float*)d_in[14];
  const float* sbe   = (const float*)d_in[15];
  const float* sW2   = (const float*)d_in[16];
  const float* sb2   = (const float*)d_in[17];
  float* out = (float*)d_out;
  char* ws = (char*)d_ws;
  (void)in_sizes; (void)n_in; (void)out_size;

  size_t o = 0;
  auto take = [&](size_t bytes) {
    void* p = ws + o;
    o += (bytes + 255) & ~(size_t)255;
    return p;
  };
  f16*   XT   = (f16*)take((size_t)160 * KPAD * 2);          // 3.2 MB
  float* H    = (float*)take((size_t)4 * NN * 256 * 4);      // 41 MB
  float* ssum = (float*)take(1024 * 4);
  float* ssq  = (float*)take(1024 * 4);
  float* ab   = (float*)take(2048 * 4);
  const size_t dynBase = o;

  // GCN buffers alias the split-K partial region (dead after k_mlp1).
  float* hw   = (float*)(ws + dynBase);
  float* hb1  = hw + (size_t)NN * 256;
  float* hb2  = hb1 + (size_t)NN * 256;
  unsigned* cnt = (unsigned*)(hb2 + (size_t)NN * 256);
  float* dinv = (float*)(cnt + NN);
  int* rowptr = (int*)(dinv + NN);
  int* cursor = rowptr + NN + 8;
  int* ecol   = cursor + NN;
  float* eval = (float*)(ecol + (EE + NN));
  size_t gcnBytes = (size_t)((char*)(eval + EE + NN) - (ws + dynBase));

  float* part = (float*)(ws + dynBase);
  int NC = 4;
  while (NC > 1) {
    size_t partBytes = (size_t)3 * NC * NN * 160 * 4;
    size_t need = dynBase + (partBytes > gcnBytes ? partBytes : gcnBytes);
    if (need <= ws_size) break;
    NC >>= 1;
  }
  const int steps_per = (KSTEPS + NC - 1) / NC;

  hipMemsetAsync(ssum, 0, 2 * 1024 * 4, stream);  // ssum + ssq (contiguous)

  // ---- subgraph branch ----
  k_prep_xt<<<dim3(157, 5), 256, 0, stream>>>(x, wf, XT);
  k_hop_gemm<<<dim3(157, NC, 3), 256, 0, stream>>>(hop1, hop2, hop3, XT, part, steps_per);
  k_mlp1<<<dim3(157, 4), 256, 0, stream>>>(x, wf, part, sW1, sb1, H, NC);
  k_stats<<<dim3(157, 4), 256, 0, stream>>>(H, ssum, ssq);
  k_bnstats<<<4, 256, 0, stream>>>(ssum, ssq, sg, sbe, ab);
  k_mlp2<<<313, 256, 0, stream>>>(H, ab, sW2, sb2, out);

  // ---- GCN branch (reuses part region, so it runs after k_mlp1) ----
  hipMemsetAsync(cnt, 0, NN * 4, stream);
  k_count<<<(EE + 255) / 256, 256, 0, stream>>>(edges, cnt);
  k_dinv<<<(NN + 255) / 256, 256, 0, stream>>>(cnt, dinv);
  k_scan<<<1, 256, 0, stream>>>(cnt, rowptr, cursor);
  k_fill<<<(EE + NN + 255) / 256, 256, 0, stream>>>(edges, dinv, cursor, ecol, eval);

  k_gemm256<<<157, 256, 0, stream>>>(x, 128, gW1, hw);
  k_prop<<<NN, 256, 0, stream>>>(hw, rowptr, ecol, eval, gb1, hb1, 256);
  k_gemm256<<<157, 256, 0, stream>>>(hb1, 256, gW2, hw);
  k_prop<<<NN, 256, 0, stream>>>(hw, rowptr, ecol, eval, gb2, hb2, 256);
  k_gemm256<<<157, 256, 0, stream>>>(hb2, 256, gW3, hw);
  k_prop<<<NN, 256, 0, stream>>>(hw, rowptr, ecol, eval, gb3, out, 512);
}